// Round 1
// 509.796 us; speedup vs baseline: 1.0559x; 1.0559x over previous
//
#include <hip/hip_runtime.h>
#include <hip/hip_bf16.h>

#define IN_CH 512
#define OUT_CH 64
#define SCAN_CHUNK 2048   // 256 threads * 8 elements

typedef __attribute__((ext_vector_type(8))) short short8;
typedef __attribute__((ext_vector_type(4))) float f32x4;

static __device__ __forceinline__ unsigned short bf16bits(float f) {
    __hip_bfloat16 h = __float2bfloat16(f);
    return *reinterpret_cast<unsigned short*>(&h);
}
static __device__ __forceinline__ float bflo(unsigned int u) {  // low ushort as bf16 -> f32
    return __uint_as_float(u << 16);
}
static __device__ __forceinline__ float bfhi(unsigned int u) {  // high ushort as bf16 -> f32
    return __uint_as_float(u & 0xffff0000u);
}

// --- fused prep: zero cnt+cursor, W[512][64] -> Wt[64][512] bf16, zero sentinel row/dinv ---
// blocks [0, zb): zero cnt+cursor (2N u32, uint4 stores)
// blocks [zb, zb+128): transpose+convert W
// block zb+128: zero hs[N] row and dinv[N]
__global__ void prep_kernel(const float* __restrict__ W, unsigned short* __restrict__ Wt,
                            unsigned int* __restrict__ cntcur, unsigned short* __restrict__ hs,
                            float* __restrict__ dinv, int N, int zb) {
    int b = blockIdx.x;
    if (b < zb) {
        unsigned int i = b * 256u + threadIdx.x;
        unsigned int tot4 = (unsigned int)N * 2u / 4u;
        if (i < tot4) {
            uint4 z = {0u, 0u, 0u, 0u};
            ((uint4*)cntcur)[i] = z;
        }
        return;
    }
    b -= zb;
    if (b < 128) {
        int i = b * 256 + threadIdx.x;   // 32768
        int k = i >> 6, n = i & 63;
        Wt[n * IN_CH + k] = bf16bits(W[i]);
        return;
    }
    if (threadIdx.x < OUT_CH) hs[(size_t)N * OUT_CH + threadIdx.x] = 0;
    if (threadIdx.x == 0) dinv[N] = 0.f;
}

// --- fused: MFMA GEMM (hs = x @ W, UNSCALED, bf16) + in-degree histogram ---
// blocks [0, GB): gemm, one wave per 16 rows. blocks [GB, ...): deg histogram, 4 edges/thread.
__global__ void __launch_bounds__(256) gemm_deg(const float* __restrict__ x,
                                                const unsigned short* __restrict__ Wt,
                                                unsigned short* __restrict__ hs, int N,
                                                const int* __restrict__ col,
                                                unsigned int* __restrict__ cnt, int E, int GB) {
    if ((int)blockIdx.x >= GB) {
        int i = ((int)blockIdx.x - GB) * 256 + threadIdx.x;
        int E4 = E >> 2;
        if (i < E4) {
            int4 c = ((const int4*)col)[i];
            atomicAdd(&cnt[c.x], 1u);
            atomicAdd(&cnt[c.y], 1u);
            atomicAdd(&cnt[c.z], 1u);
            atomicAdd(&cnt[c.w], 1u);
        } else if (i == E4) {
            for (int e = E4 * 4; e < E; ++e) atomicAdd(&cnt[col[e]], 1u);
        }
        return;
    }
    int wid = (int)((blockIdx.x * 256u + threadIdx.x) >> 6);
    int lane = threadIdx.x & 63;
    int row0 = wid * 16;
    if (row0 >= N) return;
    int m = lane & 15, q = lane >> 4;
    const float* xr = x + (size_t)(row0 + m) * IN_CH + q * 8;
    f32x4 acc[4];
#pragma unroll
    for (int t = 0; t < 4; ++t) acc[t] = (f32x4){0.f, 0.f, 0.f, 0.f};

    for (int kb = 0; kb < IN_CH; kb += 32) {
        f32x4 a0 = *(const f32x4*)(xr + kb);
        f32x4 a1 = *(const f32x4*)(xr + kb + 4);
        short8 af;
        af[0] = (short)bf16bits(a0[0]); af[1] = (short)bf16bits(a0[1]);
        af[2] = (short)bf16bits(a0[2]); af[3] = (short)bf16bits(a0[3]);
        af[4] = (short)bf16bits(a1[0]); af[5] = (short)bf16bits(a1[1]);
        af[6] = (short)bf16bits(a1[2]); af[7] = (short)bf16bits(a1[3]);
#pragma unroll
        for (int t = 0; t < 4; ++t) {
            short8 bf = *(const short8*)(Wt + (size_t)(t * 16 + m) * IN_CH + kb + q * 8);
            acc[t] = __builtin_amdgcn_mfma_f32_16x16x32_bf16(af, bf, acc[t], 0, 0, 0);
        }
    }
    // C/D layout: col = lane&15, row (within 16) = q*4 + reg
#pragma unroll
    for (int r = 0; r < 4; ++r) {
#pragma unroll
        for (int t = 0; t < 4; ++t)
            hs[(size_t)(row0 + q * 4 + r) * OUT_CH + t * 16 + m] = bf16bits(acc[t][r]);
    }
}

// --- scan A: per-chunk exclusive scan of counts padded to mult of 4 (uint4 alignment); also dinv ---
__global__ void scan_a(const unsigned int* __restrict__ cnt, float* __restrict__ dinv,
                       unsigned int* __restrict__ rowptr, unsigned int* __restrict__ blockSums, int N) {
    __shared__ unsigned int wsum[4];
    int t = threadIdx.x, b = blockIdx.x;
    int base = b * SCAN_CHUNK + t * 8;
    unsigned int p[8];
    unsigned int run = 0;
#pragma unroll
    for (int j = 0; j < 8; ++j) {
        unsigned int v = (base + j < N) ? cnt[base + j] : 0u;
        if (base + j < N) dinv[base + j] = rsqrtf((float)(v + 1u));
        p[j] = run;
        run += (v + 3u) & ~3u;   // pad to mult of 4 -> segment starts uint4-aligned
    }
    unsigned int s = run;
    unsigned int si = s;
#pragma unroll
    for (int off = 1; off < 64; off <<= 1) {
        unsigned int o = __shfl_up(si, off, 64);
        if ((t & 63) >= off) si += o;
    }
    if ((t & 63) == 63) wsum[t >> 6] = si;
    __syncthreads();
    unsigned int woff = 0;
    int w = t >> 6;
    for (int k = 0; k < w; ++k) woff += wsum[k];
    unsigned int exc = woff + si - s;
#pragma unroll
    for (int j = 0; j < 8; ++j)
        if (base + j < N) rowptr[base + j] = exc + p[j];
    if (t == 255) blockSums[b] = woff + si;
}

// --- scan B: exclusive scan of block totals (single wave, nb<=64) ---
__global__ void scan_b(const unsigned int* __restrict__ blockSums, unsigned int* __restrict__ blockOff, int nb) {
    int t = threadIdx.x;
    unsigned int s = (t < nb) ? blockSums[t] : 0u;
    unsigned int si = s;
#pragma unroll
    for (int off = 1; off < 64; off <<= 1) {
        unsigned int o = __shfl_up(si, off, 64);
        if (t >= off) si += o;
    }
    blockOff[t] = si - s;
}

// --- fill CSR: srcIdx[segment(col)] = row, 4 edges/thread. No init needed: gather clamps tails. ---
__global__ void fill_kernel(const int* __restrict__ ei, const unsigned int* __restrict__ rowptr,
                            const unsigned int* __restrict__ blockOff, unsigned int* __restrict__ cursor,
                            unsigned int* __restrict__ srcIdx, int E) {
    int E4 = E >> 2;
    int i = blockIdx.x * 256 + threadIdx.x;
    if (i < E4) {
        int4 r = ((const int4*)ei)[i];
        int4 c = ((const int4*)(ei + E))[i];
        unsigned int pos;
        pos = rowptr[c.x] + blockOff[c.x >> 11] + atomicAdd(&cursor[c.x], 1u); srcIdx[pos] = (unsigned int)r.x;
        pos = rowptr[c.y] + blockOff[c.y >> 11] + atomicAdd(&cursor[c.y], 1u); srcIdx[pos] = (unsigned int)r.y;
        pos = rowptr[c.z] + blockOff[c.z >> 11] + atomicAdd(&cursor[c.z], 1u); srcIdx[pos] = (unsigned int)r.z;
        pos = rowptr[c.w] + blockOff[c.w >> 11] + atomicAdd(&cursor[c.w], 1u); srcIdx[pos] = (unsigned int)r.w;
    } else if (i == E4) {
        for (int e = E4 * 4; e < E; ++e) {
            int r = ei[e], c = ei[E + e];
            unsigned int pos = rowptr[c] + blockOff[c >> 11] + atomicAdd(&cursor[c], 1u);
            srcIdx[pos] = (unsigned int)r;
        }
    }
}

// --- fused gather + self + bias + log_softmax. One wave/node; half-waves cover 4 edges each.
//     hs is UNSCALED: each message multiplied by dinv[src]; tail slots clamped to sentinel N
//     (dinv[N]=0, hs[N]=0) so srcIdx needs no initialization. ---
__global__ void __launch_bounds__(256) gather_kernel(const unsigned int* __restrict__ srcIdx,
                                                     const unsigned int* __restrict__ rowptr,
                                                     const unsigned int* __restrict__ blockOff,
                                                     const unsigned int* __restrict__ cnt,
                                                     const float* __restrict__ dinv,
                                                     const unsigned short* __restrict__ hs,
                                                     const float* __restrict__ bias,
                                                     float* __restrict__ out, int N) {
    int node = (int)((blockIdx.x * (unsigned long long)blockDim.x + threadIdx.x) >> 6);
    int lane = threadIdx.x & 63;
    if (node >= N) return;
    int sub = lane >> 5, ch2 = lane & 31;   // lane covers channels 2*ch2, 2*ch2+1
    unsigned int start = rowptr[node] + blockOff[node >> 11];
    unsigned int cn = cnt[node];
    unsigned int iters = (cn + 7u) >> 3;   // 8 edges per iter (4 per half-wave)
    const uint4* sp = (const uint4*)(srcIdx + start + sub * 4);
    unsigned int sent = (unsigned int)N;
    float acc0 = 0.f, acc1 = 0.f;
    for (unsigned int it = 0; it < iters; ++it) {
        uint4 iv = sp[it * 2];
        unsigned int slot = it * 8u + (unsigned int)sub * 4u;
        unsigned int i0 = (slot + 0u < cn) ? iv.x : sent;
        unsigned int i1 = (slot + 1u < cn) ? iv.y : sent;
        unsigned int i2 = (slot + 2u < cn) ? iv.z : sent;
        unsigned int i3 = (slot + 3u < cn) ? iv.w : sent;
        float d0 = dinv[i0], d1 = dinv[i1], d2 = dinv[i2], d3 = dinv[i3];
        unsigned int u0 = *(const unsigned int*)(hs + (size_t)i0 * OUT_CH + 2 * ch2);
        unsigned int u1 = *(const unsigned int*)(hs + (size_t)i1 * OUT_CH + 2 * ch2);
        unsigned int u2 = *(const unsigned int*)(hs + (size_t)i2 * OUT_CH + 2 * ch2);
        unsigned int u3 = *(const unsigned int*)(hs + (size_t)i3 * OUT_CH + 2 * ch2);
        acc0 += bflo(u0) * d0 + bflo(u1) * d1 + bflo(u2) * d2 + bflo(u3) * d3;
        acc1 += bfhi(u0) * d0 + bfhi(u1) * d1 + bfhi(u2) * d2 + bfhi(u3) * d3;
    }
    acc0 += __shfl_xor(acc0, 32, 64);
    acc1 += __shfl_xor(acc1, 32, 64);
    // self-loop term: + hs[node]*dinv[node]; whole thing scaled by dinv[node]
    float di = dinv[node];
    unsigned int us = *(const unsigned int*)(hs + (size_t)node * OUT_CH + 2 * ch2);
    acc0 = fmaf(bflo(us), di, acc0);
    acc1 = fmaf(bfhi(us), di, acc1);
    float2 bb = *(const float2*)(bias + 2 * ch2);
    float v0 = fmaf(acc0, di, bb.x);
    float v1 = fmaf(acc1, di, bb.y);
    // log_softmax over 64 channels; each half-wave holds all channels (2/lane over 32 lanes)
    float mx = fmaxf(v0, v1);
#pragma unroll
    for (int off = 16; off > 0; off >>= 1) mx = fmaxf(mx, __shfl_xor(mx, off, 64));
    float s = expf(v0 - mx) + expf(v1 - mx);
#pragma unroll
    for (int off = 16; off > 0; off >>= 1) s += __shfl_xor(s, off, 64);
    float ls = logf(s);
    if (sub == 0) {
        float2 o = {v0 - mx - ls, v1 - mx - ls};
        *(float2*)(out + (size_t)node * OUT_CH + 2 * ch2) = o;
    }
}

extern "C" void kernel_launch(void* const* d_in, const int* in_sizes, int n_in,
                              void* d_out, int out_size, void* d_ws, size_t ws_size,
                              hipStream_t stream) {
    const float* x  = (const float*)d_in[0];
    const int*   ei = (const int*)d_in[1];
    const float* W  = (const float*)d_in[2];
    const float* b  = (const float*)d_in[3];
    float* out = (float*)d_out;

    const int N = in_sizes[0] / IN_CH;   // 100000
    const int E = in_sizes[1] / 2;       // 1600000
    const int NBLK = (N + SCAN_CHUNK - 1) / SCAN_CHUNK;  // 49

    char* ws = (char*)d_ws;
    size_t o = 0;
    // cnt and cursor MUST stay adjacent (zeroed together in prep_kernel)
    unsigned int* cnt      = (unsigned int*)(ws + o); o += (size_t)N * 4;
    unsigned int* cursor   = (unsigned int*)(ws + o); o += (size_t)N * 4;
    unsigned int* rowptr   = (unsigned int*)(ws + o); o += (size_t)N * 4;
    unsigned int* blockSums= (unsigned int*)(ws + o); o += 256;
    unsigned int* blockOff = (unsigned int*)(ws + o); o += 256;
    float*        dinv     = (float*)(ws + o);        o += ((size_t)(N + 1) * 4 + 15) & ~15ull;
    unsigned int* srcIdx   = (unsigned int*)(ws + o); o += ((size_t)E + 3u * (size_t)N + 64) * 4;
    unsigned short* Wt     = (unsigned short*)(ws + o); o += (size_t)IN_CH * OUT_CH * 2;
    unsigned short* hs     = (unsigned short*)(ws + o); o += (size_t)(N + 1) * OUT_CH * 2;

    const int zb = (N * 2 / 4 + 255) / 256;       // uint4 blocks to zero cnt+cursor (196)
    const int GB = (N + 63) / 64;                 // gemm blocks (4 waves * 16 rows) = 1563
    const int DB = (E / 4 + 1 + 255) / 256;       // deg/fill blocks = 1563

    prep_kernel<<<zb + 129, 256, 0, stream>>>(W, Wt, cnt, hs, dinv, N, zb);
    gemm_deg<<<GB + DB, 256, 0, stream>>>(x, Wt, hs, N, ei + E, cnt, E, GB);
    scan_a<<<NBLK, 256, 0, stream>>>(cnt, dinv, rowptr, blockSums, N);
    scan_b<<<1, 64, 0, stream>>>(blockSums, blockOff, NBLK);
    fill_kernel<<<DB, 256, 0, stream>>>(ei, rowptr, blockOff, cursor, srcIdx, E);
    gather_kernel<<<((size_t)N * 64 + 255) / 256, 256, 0, stream>>>(srcIdx, rowptr, blockOff, cnt, dinv, hs, b, out, N);
}